// Round 11
// baseline (215.821 us; speedup 1.0000x reference)
//
#include <hip/hip_runtime.h>
#include <math.h>

#define N_TL 131072
#define GRID 2048          // 64 TLs per block, single pass
#define BLK 256

#define NFRAG 70
#define WS_CONST_OFF (NFRAG * 256)   // in uint4 units
#define NCONST 1346                  // floats in ws const block

typedef __attribute__((ext_vector_type(8))) short bfrag;
typedef __attribute__((ext_vector_type(4))) float f32x4;
typedef __attribute__((ext_vector_type(16))) float f32x16;

// RNE bf16 (weights, converted once in prep kernel)
__device__ __forceinline__ unsigned short f2bf_rne(float x) {
  unsigned int u = __float_as_uint(x);
  return (unsigned short)((u + 0x7fffu + ((u >> 16) & 1u)) >> 16);
}
// round-half-up pack of 2 floats -> bf16x2 via v_perm (3 VALU)
__device__ __forceinline__ unsigned int pack2(float a, float b) {
  return __builtin_amdgcn_perm(__float_as_uint(b) + 0x8000u,
                               __float_as_uint(a) + 0x8000u, 0x07060302u);
}
__device__ __forceinline__ float lo16(unsigned int u) { return __uint_as_float(u << 16); }
__device__ __forceinline__ float hi16(unsigned int u) { return __uint_as_float(u & 0xffff0000u); }
__device__ __forceinline__ f32x4 mfma16(bfrag a, bfrag b, f32x4 c) {
  return __builtin_amdgcn_mfma_f32_16x16x32_bf16(a, b, c, 0, 0, 0);
}
__device__ __forceinline__ f32x16 mfma32(bfrag a, bfrag b, f32x16 c) {
  return __builtin_amdgcn_mfma_f32_32x32x16_bf16(a, b, c, 0, 0, 0);
}

// 16x16x32 weight A-fragment (W^T): A[m=col0+(lane&15)][k=k0+quad*8+j]
__device__ __forceinline__ bfrag load_wfragT(const float* __restrict__ w, int ncols,
                                             int col0, int k0, int lane, int K, float scale) {
  const int mm = lane & 15, qq = lane >> 4;
  bfrag f;
  #pragma unroll
  for (int j = 0; j < 8; ++j) {
    const int k = k0 + qq * 8 + j;
    const float v = (k < K) ? w[(size_t)k * ncols + col0 + mm] * scale : 0.f;
    f[j] = (short)f2bf_rne(v);
  }
  return f;
}
// 32x32x16 weight A-fragment: A[m=m0+(lane&31)][k=k0+(lane>>5)*8+j]
__device__ __forceinline__ bfrag load_wfragT32(const float* __restrict__ w, int ncols,
                                               int m0, int k0, int lane, int K, float scale) {
  const int mm = lane & 31, q1 = lane >> 5;
  bfrag f;
  #pragma unroll
  for (int j = 0; j < 8; ++j) {
    const int k = k0 + q1 * 8 + j;
    const float v = (k < K) ? w[(size_t)k * ncols + m0 + mm] * scale : 0.f;
    f[j] = (short)f2bf_rne(v);
  }
  return f;
}

// One dwordx4 load of a pre-packed fragment from the workspace table.
__device__ __forceinline__ bfrag ldfrag(const uint4* __restrict__ WF, int f, int tid) {
  uint4 u = WF[f * 256 + tid];
  return *reinterpret_cast<bfrag*>(&u);
}

// 32x32 B-frag from row-major bf16 LDS: row fixed per lane, k-step kk (16 elems)
__device__ __forceinline__ bfrag ldb32f(const unsigned short* arr, int stride, int row,
                                        int kk, int q1) {
  return *reinterpret_cast<const bfrag*>(&arr[row * stride + kk * 16 + q1 * 8]);
}
// 32x32 C: col=lane&31, row=(reg&3)+8*(reg>>2)+4*(lane>>5)
__device__ __forceinline__ f32x16 binit32(const float* bias, int chBase, int q1) {
  f32x16 a;
  #pragma unroll
  for (int g = 0; g < 4; ++g) {
    const f32x4 bb = *reinterpret_cast<const f32x4*>(&bias[chBase + g * 8 + q1 * 4]);
    a[g * 4 + 0] = bb[0]; a[g * 4 + 1] = bb[1];
    a[g * 4 + 2] = bb[2]; a[g * 4 + 3] = bb[3];
  }
  return a;
}
__device__ __forceinline__ void st32(unsigned short* arr, int stride, int row,
                                     int chBase, int q1, f32x16 acc, bool relu) {
  #pragma unroll
  for (int g = 0; g < 4; ++g) {
    float a0 = acc[g * 4 + 0], a1 = acc[g * 4 + 1];
    float a2 = acc[g * 4 + 2], a3 = acc[g * 4 + 3];
    if (relu) {
      a0 = fmaxf(a0, 0.f); a1 = fmaxf(a1, 0.f);
      a2 = fmaxf(a2, 0.f); a3 = fmaxf(a3, 0.f);
    }
    uint2 u;
    u.x = pack2(a0, a1);
    u.y = pack2(a2, a3);
    *reinterpret_cast<uint2*>(&arr[row * stride + chBase + g * 8 + q1 * 4]) = u;
  }
}

// B-operand (activations) for 16x16 path (out-proj only)
#define LDBACT(arr, stride, nt, kk) \
  (*reinterpret_cast<const bfrag*>(&(arr)[((nt) * 16 + m) * (stride) + (kk) * 32 + quad * 8]))

// ============ prep kernel: one-time weight->bf16-fragment conversion ============
// frag ids: 0-7 wL2[kk] | 8-19 wQKV[t][kk] | 20-21 wOUT2 (16x16) | 22-25 wL1[t][kk] |
//           26-29 wP1[t][kk] | 30-45 wP2[t][kk] | 46-69 wH1[t][kk]
__global__ __launch_bounds__(BLK)
void prep_weights(const float* __restrict__ lane_w1, const float* __restrict__ lane_b1,
                  const float* __restrict__ lane_w2, const float* __restrict__ lane_b2,
                  const float* __restrict__ attn_in_w, const float* __restrict__ attn_in_b,
                  const float* __restrict__ attn_out_w, const float* __restrict__ attn_out_b,
                  const float* __restrict__ phase_w1, const float* __restrict__ phase_b1,
                  const float* __restrict__ phase_w2, const float* __restrict__ phase_b2,
                  const float* __restrict__ region_table,
                  const float* __restrict__ head_w1, const float* __restrict__ head_b1,
                  const float* __restrict__ head_w2, const float* __restrict__ head_b2,
                  const float* __restrict__ log_std,
                  uint4* __restrict__ ws) {
  const int f = blockIdx.x;
  const int tid = threadIdx.x;
  const int wv = tid >> 6, lane = tid & 63;
  const int mb = wv >> 1;                     // wave quadrant: Mi base, Ni = wv&1
  bfrag r;
  if (f < 8) {
    r = load_wfragT32(lane_w2, 64, mb * 32, f * 16, lane, 128, 1.f);
  } else if (f < 20) {
    const int t = (f - 8) >> 2, kk = (f - 8) & 3;
    r = load_wfragT32(attn_in_w, 192, (mb + 2 * t) * 32, kk * 16, lane, 64,
                      t == 0 ? 0.25f : 1.f);  // t=0 tiles are Q: fold 1/sqrt(HD)
  } else if (f < 22) {
    r = load_wfragT(attn_out_w, 64, wv * 16, (f - 20) * 32, lane, 64, 0.25f);  // mean folded
  } else if (f < 26) {
    const int t = (f - 22) >> 1, kk = (f - 22) & 1;
    r = load_wfragT32(lane_w1, 128, (mb + 2 * t) * 32, kk * 16, lane, 3, 1.f);
  } else if (f < 30) {
    const int t = (f - 26) >> 1, kk = (f - 26) & 1;
    r = load_wfragT32(phase_w1, 128, (mb + 2 * t) * 32, kk * 16, lane, 5, 1.f);
  } else if (f < 46) {
    const int t = (f - 30) >> 3, kk = (f - 30) & 7;
    r = load_wfragT32(phase_w2, 128, (mb + 2 * t) * 32, kk * 16, lane, 128, 1.f);
  } else {
    const int t = (f - 46) / 12, kk = (f - 46) % 12;
    r = load_wfragT32(head_w1, 128, (mb + 2 * t) * 32, kk * 16, lane, 192, 1.f);
  }
  ws[f * 256 + tid] = *reinterpret_cast<uint4*>(&r);

  if (f == 0) {
    // const block: b1[128] b2[64] bin[192] bout[64] pb1[128] pb2[128]
    //              rbias[512] hw2[128] consts[2]  (main kernel LDS-stages 0..1215)
    float* wc = reinterpret_cast<float*>(ws + WS_CONST_OFF);
    for (int i = tid; i < NCONST; i += BLK) {
      float v;
      if (i < 128)       v = lane_b1[i];
      else if (i < 192)  v = lane_b2[i - 128];
      else if (i < 384)  { const int j = i - 192; v = attn_in_b[j] * ((j < 64) ? 0.25f : 1.f); }
      else if (i < 448)  v = attn_out_b[i - 384];
      else if (i < 576)  v = phase_b1[i - 448];
      else if (i < 704)  v = phase_b2[i - 576];
      else if (i < 1216) {
        const int g = (i - 704) >> 7, c = (i - 704) & 127;
        float a = head_b1[c];
        #pragma unroll
        for (int j = 0; j < 8; ++j) a += region_table[g * 8 + j] * head_w1[(192 + j) * 128 + c];
        v = a;
      }
      else if (i < 1344) v = head_w2[i - 1216];
      else if (i == 1344) v = head_b2[0];
      else               v = log_std[0];
      wc[i] = v;
    }
  }
}

// LDS: 53.0 KB -> 52 KiB alloc -> 3 blocks/CU (12 waves/CU).
// feat split into ctx[64*72] + pl2out overlay on union tail + emb (B-part-dead).
struct alignas(16) SmemF {
  union {
    unsigned short qkv[64 * 200];  // A: qkv bf16 during attention (25.6 KB)
    unsigned short h[64 * 136];    // A: layer1 out (dead before qkv write)
    unsigned short ph[64 * 136];   // B: pL1 out; head-L1 out (17408 B of union)
  };
  unsigned short emb[64 * 72];     // A: emb; om[16][264] overlays (9.2 KB)
                                   // B: tail of pl2out overlay
  unsigned short xbuf[64 * 32];    // A layer1 input / B phase-L1 input (4 KB)
  unsigned short ctx[64 * 72];     // attention context, persists A->B (9.2 KB)
  float b1[128], b2[64], bin[192], bout[64];
  float pb1[128], pb2[128];
  float rbias[4][128];             // head_b1 + region[g] @ head_w1[192:200,:]
  float consts[2];
};

__global__ __launch_bounds__(BLK, 3)
void fused_policy(const float* __restrict__ queue,
                  const float* __restrict__ waiting,
                  const float* __restrict__ phase_onehot,
                  const float* __restrict__ elapsed,
                  const int* __restrict__ region_ids,
                  const float* __restrict__ noise,
                  const uint4* __restrict__ WF,     // pre-packed frag table + consts
                  float* __restrict__ out) {
  __shared__ SmemF S;
  const int tid  = threadIdx.x;
  const int wv   = tid >> 6;
  const int lane = tid & 63;
  const int m    = lane & 15;
  const int quad = lane >> 4;
  const int n32  = lane & 31;
  const int q1   = lane >> 5;
  const int mb   = wv >> 1;                  // 32x32 quadrant: Mi ∈ {mb, mb+2, ...}
  const int row64 = (wv & 1) * 32 + n32;     // Ni*32 + n32
  const int n0   = blockIdx.x * 64;          // 64 TLs per block
  const float* wsf = reinterpret_cast<const float*>(WF + WS_CONST_OFF);
  // B-part pL2 output: 64x136 bf16 overlay on union tail + emb (dead in B-part)
  unsigned short* pl2out =
      reinterpret_cast<unsigned short*>(reinterpret_cast<char*>(&S) + 64 * 136 * 2);

  // ---- A-part weight fragments (B frags loaded AFTER A loop) ----
  bfrag wL1[2][2], wL2[8], wQKV[3][4], wOUT2[2];
  #pragma unroll
  for (int kk = 0; kk < 8; ++kk) wL2[kk] = ldfrag(WF, kk, tid);
  #pragma unroll
  for (int t = 0; t < 3; ++t)
    #pragma unroll
    for (int kk = 0; kk < 4; ++kk) wQKV[t][kk] = ldfrag(WF, 8 + t * 4 + kk, tid);
  #pragma unroll
  for (int kk = 0; kk < 2; ++kk) wOUT2[kk] = ldfrag(WF, 20 + kk, tid);
  #pragma unroll
  for (int t = 0; t < 2; ++t)
    #pragma unroll
    for (int kk = 0; kk < 2; ++kk) wL1[t][kk] = ldfrag(WF, 22 + t * 2 + kk, tid);

  // ---- stage constants b1..rbias (1216 floats); consts separately ----
  {
    const float2* src = reinterpret_cast<const float2*>(wsf);
    float2* dst = reinterpret_cast<float2*>(&S.b1[0]);
    for (int i = tid; i < 608; i += BLK) dst[i] = src[i];
  }
  if (tid < 2) S.consts[tid] = wsf[1344 + tid];
  // stage x for sub-iter 0 (16 TLs x 4 lane-rows, K padded to 32)
  {
    const int r = tid >> 2, seg = tid & 3;
    uint4 z = {0, 0, 0, 0};
    if (seg == 0) {
      const int gl = n0 * 4 + r;
      z.x = pack2(queue[gl], waiting[gl]);
      z.y = pack2(elapsed[n0 + (r >> 2)], 0.f);
    }
    *reinterpret_cast<uint4*>(&S.xbuf[r * 32 + seg * 8]) = z;
  }
  __syncthreads();

  // ================= A-part: 4 sub-iters of 16 TLs =================
  #pragma unroll 1
  for (int s = 0; s < 4; ++s) {
    const int tl0 = n0 + s * 16;

    // ---- layer1 (32x32, K=32 zero-padded): h^T = w1^T @ x, bias in acc-init ----
    {
      f32x16 acc[2];
      #pragma unroll
      for (int t = 0; t < 2; ++t) acc[t] = binit32(S.b1, (mb + 2 * t) * 32, q1);
      #pragma unroll
      for (int kk = 0; kk < 2; ++kk) {
        const bfrag b = ldb32f(S.xbuf, 32, row64, kk, q1);
        acc[0] = mfma32(wL1[0][kk], b, acc[0]);
        acc[1] = mfma32(wL1[1][kk], b, acc[1]);
      }
      #pragma unroll
      for (int t = 0; t < 2; ++t) st32(S.h, 136, row64, (mb + 2 * t) * 32, q1, acc[t], true);
    }
    __syncthreads();

    // ---- layer2 (32x32, K=128): emb^T = w2^T @ h ----
    {
      f32x16 acc = binit32(S.b2, mb * 32, q1);
      #pragma unroll
      for (int kk = 0; kk < 8; ++kk)
        acc = mfma32(wL2[kk], ldb32f(S.h, 136, row64, kk, q1), acc);
      st32(S.emb, 72, row64, mb * 32, q1, acc, true);
    }
    __syncthreads();

    // ---- QKV (32x32, K=64): qkv^T = Win^T @ emb (bf16 out); stage next x ----
    {
      f32x16 acc[3];
      #pragma unroll
      for (int t = 0; t < 3; ++t) acc[t] = binit32(S.bin, (mb + 2 * t) * 32, q1);
      #pragma unroll
      for (int kk = 0; kk < 4; ++kk) {
        const bfrag b = ldb32f(S.emb, 72, row64, kk, q1);
        #pragma unroll
        for (int t = 0; t < 3; ++t) acc[t] = mfma32(wQKV[t][kk], b, acc[t]);
      }
      #pragma unroll
      for (int t = 0; t < 3; ++t)
        st32(S.qkv, 200, row64, (mb + 2 * t) * 32, q1, acc[t], false);

      const int r = tid >> 2, seg = tid & 3;
      uint4 z = {0, 0, 0, 0};
      if (s < 3) {      // prefetch next sub-iter's lane inputs
        if (seg == 0) {
          const int gl = (tl0 + 16) * 4 + r;
          z.x = pack2(queue[gl], waiting[gl]);
          z.y = pack2(elapsed[tl0 + 16 + (r >> 2)], 0.f);
        }
      } else {          // stage B phase-L1 input (64 TLs, K padded to 32)
        if (seg == 0) {
          const float4 p = *reinterpret_cast<const float4*>(&phase_onehot[(n0 + r) * 4]);
          z.x = pack2(p.x, p.y);
          z.y = pack2(p.z, p.w);
          z.z = pack2(elapsed[n0 + r], 0.f);
        }
      }
      *reinterpret_cast<uint4*>(&S.xbuf[r * 32 + seg * 8]) = z;
    }
    __syncthreads();

    // ---- attention: 16 threads/TL = 4 heads x 4 queries; b128 LDS reads ----
    {
      const int tl = tid >> 4, l16 = tid & 15;
      const int hh = l16 >> 2, lq = l16 & 3;
      const uint4* qp = reinterpret_cast<const uint4*>(
          &S.qkv[(tl * 4 + lq) * 200 + hh * 16]);
      const uint4 qA = qp[0], qB = qp[1];
      const unsigned int qu[8] = {qA.x, qA.y, qA.z, qA.w, qB.x, qB.y, qB.z, qB.w};
      float qlo[8], qhi[8];
      #pragma unroll
      for (int j = 0; j < 8; ++j) { qlo[j] = lo16(qu[j]); qhi[j] = hi16(qu[j]); }
      float sc[4];
      #pragma unroll
      for (int lk = 0; lk < 4; ++lk) {
        const uint4* kp = reinterpret_cast<const uint4*>(
            &S.qkv[(tl * 4 + lk) * 200 + 64 + hh * 16]);
        const uint4 kA = kp[0], kB = kp[1];
        const unsigned int ku[8] = {kA.x, kA.y, kA.z, kA.w, kB.x, kB.y, kB.z, kB.w};
        float tx = 0.f, ty = 0.f;
        #pragma unroll
        for (int j = 0; j < 8; ++j) {
          tx += qlo[j] * lo16(ku[j]);
          ty += qhi[j] * hi16(ku[j]);
        }
        sc[lk] = tx + ty;   // 1/sqrt(HD) folded into Q weights/bias
      }
      const float mx = fmaxf(fmaxf(sc[0], sc[1]), fmaxf(sc[2], sc[3]));
      const float e0 = __expf(sc[0] - mx), e1 = __expf(sc[1] - mx);
      const float e2 = __expf(sc[2] - mx), e3 = __expf(sc[3] - mx);
      const float inv = 1.f / (e0 + e1 + e2 + e3);
      const float pr[4] = {e0 * inv, e1 * inv, e2 * inv, e3 * inv};
      float olo[8], ohi[8];
      #pragma unroll
      for (int j = 0; j < 8; ++j) { olo[j] = 0.f; ohi[j] = 0.f; }
      #pragma unroll
      for (int lk = 0; lk < 4; ++lk) {
        const uint4* vp = reinterpret_cast<const uint4*>(
            &S.qkv[(tl * 4 + lk) * 200 + 128 + hh * 16]);
        const uint4 vA = vp[0], vB = vp[1];
        const unsigned int vu[8] = {vA.x, vA.y, vA.z, vA.w, vB.x, vB.y, vB.z, vB.w};
        const float p = pr[lk];
        #pragma unroll
        for (int j = 0; j < 8; ++j) {
          olo[j] += p * lo16(vu[j]);
          ohi[j] += p * hi16(vu[j]);
        }
      }
      // mean over queries folded into wOUT; raw o -> om[tl][lq*64 + hh*16 + d]
      unsigned short* om = S.emb;
      const int base = tl * 264 + lq * 64 + hh * 16;
      *reinterpret_cast<uint4*>(&om[base]) =
          make_uint4(pack2(olo[0], ohi[0]), pack2(olo[1], ohi[1]),
                     pack2(olo[2], ohi[2]), pack2(olo[3], ohi[3]));
      *reinterpret_cast<uint4*>(&om[base + 8]) =
          make_uint4(pack2(olo[4], ohi[4]), pack2(olo[5], ohi[5]),
                     pack2(olo[6], ohi[6]), pack2(olo[7], ohi[7]));
    }
    __syncthreads();

    // ---- out-proj (16x16, K=256, mean folded) -> ctx rows s*16.. ----
    {
      const int oc0 = wv * 16 + quad * 4;
      f32x4 acc = *reinterpret_cast<const f32x4*>(&S.bout[oc0]);
      #pragma unroll
      for (int kk = 0; kk < 8; ++kk)
        acc = mfma16(wOUT2[kk & 1], LDBACT(S.emb, 264, 0, kk), acc);
      uint2 u;
      u.x = pack2(acc[0], acc[1]);
      u.y = pack2(acc[2], acc[3]);
      *reinterpret_cast<uint2*>(&S.ctx[(s * 16 + m) * 72 + oc0]) = u;
    }
    // no barrier: next layer1 writes S.h (attn readers of qkv passed barrier);
    // ctx readers are behind the post-loop barrier.
  }
  __syncthreads();

  // ================= B-part: 64 TLs =================
  __builtin_amdgcn_sched_barrier(0);
  bfrag wP1[2][2], wP2[2][8], wH1[2][12];
  #pragma unroll
  for (int t = 0; t < 2; ++t) {
    #pragma unroll
    for (int kk = 0; kk < 2; ++kk)  wP1[t][kk] = ldfrag(WF, 26 + t * 2 + kk, tid);
    #pragma unroll
    for (int kk = 0; kk < 8; ++kk)  wP2[t][kk] = ldfrag(WF, 30 + t * 8 + kk, tid);
    #pragma unroll
    for (int kk = 0; kk < 12; ++kk) wH1[t][kk] = ldfrag(WF, 46 + t * 12 + kk, tid);
  }

  // ---- phase L1 (32x32, K=32 zero-padded) -> ph ----
  {
    f32x16 acc[2];
    #pragma unroll
    for (int t = 0; t < 2; ++t) acc[t] = binit32(S.pb1, (mb + 2 * t) * 32, q1);
    #pragma unroll
    for (int kk = 0; kk < 2; ++kk) {
      const bfrag b = ldb32f(S.xbuf, 32, row64, kk, q1);
      acc[0] = mfma32(wP1[0][kk], b, acc[0]);
      acc[1] = mfma32(wP1[1][kk], b, acc[1]);
    }
    #pragma unroll
    for (int t = 0; t < 2; ++t) st32(S.ph, 136, row64, (mb + 2 * t) * 32, q1, acc[t], true);
  }
  __syncthreads();

  // ---- phase L2 (32x32, K=128) -> pl2out (overlay, stride 136) ----
  {
    f32x16 acc[2];
    #pragma unroll
    for (int t = 0; t < 2; ++t) acc[t] = binit32(S.pb2, (mb + 2 * t) * 32, q1);
    #pragma unroll
    for (int kk = 0; kk < 8; ++kk) {
      const bfrag b = ldb32f(S.ph, 136, row64, kk, q1);
      acc[0] = mfma32(wP2[0][kk], b, acc[0]);
      acc[1] = mfma32(wP2[1][kk], b, acc[1]);
    }
    #pragma unroll
    for (int t = 0; t < 2; ++t)
      st32(pl2out, 136, row64, (mb + 2 * t) * 32, q1, acc[t], true);
  }
  __syncthreads();

  // ---- head L1 (32x32, K=192): kk 0-3 from ctx, 4-11 from pl2out; rbias init ----
  {
    int rg = region_ids[n0 + row64];
    rg = rg < 0 ? 0 : (rg > 3 ? 3 : rg);
    f32x16 acc[2];
    #pragma unroll
    for (int t = 0; t < 2; ++t) acc[t] = binit32(S.rbias[rg], (mb + 2 * t) * 32, q1);
    #pragma unroll
    for (int kk = 0; kk < 4; ++kk) {
      const bfrag b = ldb32f(S.ctx, 72, row64, kk, q1);
      acc[0] = mfma32(wH1[0][kk], b, acc[0]);
      acc[1] = mfma32(wH1[1][kk], b, acc[1]);
    }
    #pragma unroll
    for (int kk = 4; kk < 12; ++kk) {
      const bfrag b = ldb32f(pl2out, 136, row64, kk - 4, q1);
      acc[0] = mfma32(wH1[0][kk], b, acc[0]);
      acc[1] = mfma32(wH1[1][kk], b, acc[1]);
    }
    #pragma unroll
    for (int t = 0; t < 2; ++t) st32(S.ph, 136, row64, (mb + 2 * t) * 32, q1, acc[t], true);
  }
  __syncthreads();

  // ---- head L2 (128->1) + gaussian: 4 threads/TL; hw2 from L2-cached consts ----
  {
    const int tl = tid >> 2, s4 = tid & 3;   // 64 TLs x 4 threads
    const float* hw2g = wsf + 1216;
    const uint4* hp = reinterpret_cast<const uint4*>(&S.ph[tl * 136 + s4 * 32]);
    const uint4 h0 = hp[0], h1 = hp[1], h2 = hp[2], h3 = hp[3];
    const unsigned int hu[16] = {h0.x, h0.y, h0.z, h0.w, h1.x, h1.y, h1.z, h1.w,
                                 h2.x, h2.y, h2.z, h2.w, h3.x, h3.y, h3.z, h3.w};
    float t = 0.f;
    #pragma unroll
    for (int j = 0; j < 16; ++j) {
      t += lo16(hu[j]) * hw2g[s4 * 32 + 2 * j];
      t += hi16(hu[j]) * hw2g[s4 * 32 + 2 * j + 1];
    }
    t += __shfl_xor(t, 1);
    t += __shfl_xor(t, 2);
    if (s4 == 0) {
      const int n = n0 + tl;
      const float means = t + S.consts[0];
      const float ls = S.consts[1];
      const float nz = noise[n];
      const float a = means + __expf(ls) * nz;
      out[n] = fminf(fmaxf(a, -1.f), 1.f);
      // (actions - means) == std*noise exactly -> log_prob independent of means
      out[N_TL + n] = -0.5f * (nz * nz + 2.f * ls + 1.8378770664093453f);
    }
  }
}

extern "C" void kernel_launch(void* const* d_in, const int* in_sizes, int n_in,
                              void* d_out, int out_size, void* d_ws, size_t ws_size,
                              hipStream_t stream) {
  const float* queue        = (const float*)d_in[0];
  const float* waiting      = (const float*)d_in[1];
  const float* phase_onehot = (const float*)d_in[2];
  const float* elapsed      = (const float*)d_in[3];
  const int*   region_ids   = (const int*)d_in[4];
  const float* noise        = (const float*)d_in[5];
  const float* lane_w1      = (const float*)d_in[6];
  const float* lane_b1      = (const float*)d_in[7];
  const float* lane_w2      = (const float*)d_in[8];
  const float* lane_b2      = (const float*)d_in[9];
  const float* attn_in_w    = (const float*)d_in[10];
  const float* attn_in_b    = (const float*)d_in[11];
  const float* attn_out_w   = (const float*)d_in[12];
  const float* attn_out_b   = (const float*)d_in[13];
  const float* phase_w1     = (const float*)d_in[14];
  const float* phase_b1     = (const float*)d_in[15];
  const float* phase_w2     = (const float*)d_in[16];
  const float* phase_b2     = (const float*)d_in[17];
  const float* region_table = (const float*)d_in[18];
  const float* head_w1      = (const float*)d_in[19];
  const float* head_b1      = (const float*)d_in[20];
  const float* head_w2      = (const float*)d_in[21];
  const float* head_b2      = (const float*)d_in[22];
  const float* log_std      = (const float*)d_in[23];

  float* out = (float*)d_out;
  uint4* ws  = (uint4*)d_ws;       // 70*256*16B frag table + 1346 f32 consts (~292 KB)
  (void)ws_size;

  hipLaunchKernelGGL(prep_weights, dim3(NFRAG), dim3(BLK), 0, stream,
                     lane_w1, lane_b1, lane_w2, lane_b2,
                     attn_in_w, attn_in_b, attn_out_w, attn_out_b,
                     phase_w1, phase_b1, phase_w2, phase_b2, region_table,
                     head_w1, head_b1, head_w2, head_b2, log_std, ws);

  hipLaunchKernelGGL(fused_policy, dim3(GRID), dim3(BLK), 0, stream,
                     queue, waiting, phase_onehot, elapsed, region_ids, noise,
                     (const uint4*)ws, out);
}

// Round 12
// 174.780 us; speedup vs baseline: 1.2348x; 1.2348x over previous
//
#include <hip/hip_runtime.h>
#include <math.h>

#define N_TL 131072
#define GRID 2048          // 64 TLs per block, single pass
#define BLK 256

#define NFRAG 36
#define WS_CONST_OFF (NFRAG * 256)   // in uint4 units
#define NCONST 1346                  // floats in ws const block

typedef __attribute__((ext_vector_type(8))) short bfrag;
typedef __attribute__((ext_vector_type(4))) float f32x4;

// RNE bf16 (weights, converted once in prep kernel)
__device__ __forceinline__ unsigned short f2bf_rne(float x) {
  unsigned int u = __float_as_uint(x);
  return (unsigned short)((u + 0x7fffu + ((u >> 16) & 1u)) >> 16);
}
// round-half-up pack of 2 floats -> bf16x2 via v_perm (3 VALU)
__device__ __forceinline__ unsigned int pack2(float a, float b) {
  return __builtin_amdgcn_perm(__float_as_uint(b) + 0x8000u,
                               __float_as_uint(a) + 0x8000u, 0x07060302u);
}
__device__ __forceinline__ float lo16(unsigned int u) { return __uint_as_float(u << 16); }
__device__ __forceinline__ float hi16(unsigned int u) { return __uint_as_float(u & 0xffff0000u); }
__device__ __forceinline__ f32x4 mfma16(bfrag a, bfrag b, f32x4 c) {
  return __builtin_amdgcn_mfma_f32_16x16x32_bf16(a, b, c, 0, 0, 0);
}

// Weight A-fragment (W^T): A[m=col0+(lane&15)][k=k0+quad*8+j] = W[k][col]*scale, 0 for k>=K.
__device__ __forceinline__ bfrag load_wfragT(const float* __restrict__ w, int ncols,
                                             int col0, int k0, int lane, int K, float scale) {
  const int mm = lane & 15, qq = lane >> 4;
  bfrag f;
  #pragma unroll
  for (int j = 0; j < 8; ++j) {
    const int k = k0 + qq * 8 + j;
    const float v = (k < K) ? w[(size_t)k * ncols + col0 + mm] * scale : 0.f;
    f[j] = (short)f2bf_rne(v);
  }
  return f;
}

// One dwordx4 load of a pre-packed fragment from the workspace table.
__device__ __forceinline__ bfrag ldfrag(const uint4* __restrict__ WF, int f, int tid) {
  uint4 u = WF[f * 256 + tid];
  return *reinterpret_cast<bfrag*>(&u);
}

// B-operand (activations) from row-major bf16 LDS
#define LDBACT(arr, stride, nt, kk) \
  (*reinterpret_cast<const bfrag*>(&(arr)[((nt) * 16 + m) * (stride) + (kk) * 32 + quad * 8]))

// ============ prep kernel: one-time weight->bf16-fragment conversion ============
// frag ids: 0-1 wL1 | 2-5 wL2 | 6-11 wQKV[Mi][kk] | 12-13 wOUT2 |
//           14-15 wP1 | 16-23 wP2[Mi][kk] | 24-35 wH1[Mi][kk]
__global__ __launch_bounds__(BLK)
void prep_weights(const float* __restrict__ lane_w1, const float* __restrict__ lane_b1,
                  const float* __restrict__ lane_w2, const float* __restrict__ lane_b2,
                  const float* __restrict__ attn_in_w, const float* __restrict__ attn_in_b,
                  const float* __restrict__ attn_out_w, const float* __restrict__ attn_out_b,
                  const float* __restrict__ phase_w1, const float* __restrict__ phase_b1,
                  const float* __restrict__ phase_w2, const float* __restrict__ phase_b2,
                  const float* __restrict__ region_table,
                  const float* __restrict__ head_w1, const float* __restrict__ head_b1,
                  const float* __restrict__ head_w2, const float* __restrict__ head_b2,
                  const float* __restrict__ log_std,
                  uint4* __restrict__ ws) {
  const int f = blockIdx.x;
  const int tid = threadIdx.x;
  const int wv = tid >> 6, lane = tid & 63;
  bfrag r;
  if (f < 2) {
    r = load_wfragT(lane_w1, 128, (wv * 2 + f) * 16, 0, lane, 3, 1.f);
  } else if (f < 6) {
    r = load_wfragT(lane_w2, 64, wv * 16, (f - 2) * 32, lane, 128, 1.f);
  } else if (f < 12) {
    const int Mi = (f - 6) >> 1, kk = (f - 6) & 1;
    r = load_wfragT(attn_in_w, 192, (wv + Mi * 4) * 16, kk * 32, lane, 64,
                    Mi == 0 ? 0.25f : 1.f);          // fold 1/sqrt(HD) into Q
  } else if (f < 14) {
    r = load_wfragT(attn_out_w, 64, wv * 16, (f - 12) * 32, lane, 64, 0.25f);  // mean folded
  } else if (f < 16) {
    r = load_wfragT(phase_w1, 128, (wv * 2 + (f - 14)) * 16, 0, lane, 5, 1.f);
  } else if (f < 24) {
    const int Mi = (f - 16) >> 2, kk = (f - 16) & 3;
    r = load_wfragT(phase_w2, 128, (wv * 2 + Mi) * 16, kk * 32, lane, 128, 1.f);
  } else {
    const int Mi = (f - 24) / 6, kk = (f - 24) % 6;
    r = load_wfragT(head_w1, 128, (wv * 2 + Mi) * 16, kk * 32, lane, 192, 1.f);
  }
  ws[f * 256 + tid] = *reinterpret_cast<uint4*>(&r);

  if (f == 0) {
    // const block: b1[128] b2[64] bin[192] bout[64] pb1[128] pb2[128]
    //              rbias[512] hw2[128] consts[2]; main kernel LDS-stages 0..1215
    float* wc = reinterpret_cast<float*>(ws + WS_CONST_OFF);
    for (int i = tid; i < NCONST; i += BLK) {
      float v;
      if (i < 128)       v = lane_b1[i];
      else if (i < 192)  v = lane_b2[i - 128];
      else if (i < 384)  { const int j = i - 192; v = attn_in_b[j] * ((j < 64) ? 0.25f : 1.f); }
      else if (i < 448)  v = attn_out_b[i - 384];
      else if (i < 576)  v = phase_b1[i - 448];
      else if (i < 704)  v = phase_b2[i - 576];
      else if (i < 1216) {
        const int g = (i - 704) >> 7, c = (i - 704) & 127;
        float a = head_b1[c];
        #pragma unroll
        for (int j = 0; j < 8; ++j) a += region_table[g * 8 + j] * head_w1[(192 + j) * 128 + c];
        v = a;
      }
      else if (i < 1344) v = head_w2[i - 1216];
      else if (i == 1344) v = head_b2[0];
      else               v = log_std[0];
      wc[i] = v;
    }
  }
}

// LDS: 52992 B -> 53248 alloc -> 3 blocks/CU (12 waves/CU; R11 confirmed residency
// at this alloc size). hw2/ridx/consts moved out of LDS (global, L2-cached).
struct alignas(16) SmemF {
  union {
    unsigned short qkv[64 * 200];  // A: qkv bf16 during attention (25.6 KB)
    unsigned short h[64 * 136];    // A: layer1 out (dead before qkv write)
    unsigned short ph[64 * 136];   // B: pL1 out; head-L1 out (17408 B of union)
  };
  unsigned short emb[64 * 72];     // A: emb; om[16][264] overlays (9.2 KB)
                                   // B: tail of pl2out overlay
  unsigned short xbuf[64 * 32];    // A layer1 input / B phase-L1 input (4 KB)
  unsigned short ctx[64 * 72];     // attention context, persists A->B (9.2 KB)
  float b1[128], b2[64], bin[192], bout[64];
  float pb1[128], pb2[128];
  float rbias[4][128];             // head_b1 + region[g] @ head_w1[192:200,:]
};

__global__ __launch_bounds__(BLK, 3)
void fused_policy(const float* __restrict__ queue,
                  const float* __restrict__ waiting,
                  const float* __restrict__ phase_onehot,
                  const float* __restrict__ elapsed,
                  const int* __restrict__ region_ids,
                  const float* __restrict__ noise,
                  const uint4* __restrict__ WF,     // pre-packed frag table + consts
                  float* __restrict__ out) {
  __shared__ SmemF S;
  const int tid  = threadIdx.x;
  const int wv   = tid >> 6;
  const int lane = tid & 63;
  const int m    = lane & 15;
  const int quad = lane >> 4;
  const int n0   = blockIdx.x * 64;         // 64 TLs per block
  const float* wsf = reinterpret_cast<const float*>(WF + WS_CONST_OFF);
  // B-part pL2 output: 64x136 bf16 overlay on union tail + emb (dead in B-part)
  unsigned short* pl2out =
      reinterpret_cast<unsigned short*>(reinterpret_cast<char*>(&S) + 64 * 136 * 2);

  // ---- A-part weight fragments: 14 coalesced dwordx4 loads (B frags AFTER A loop) ----
  bfrag wL1[2], wL2[4], wQKV[3][2], wOUT2[2];
  #pragma unroll
  for (int Mi = 0; Mi < 2; ++Mi) wL1[Mi] = ldfrag(WF, Mi, tid);
  #pragma unroll
  for (int kk = 0; kk < 4; ++kk) wL2[kk] = ldfrag(WF, 2 + kk, tid);
  #pragma unroll
  for (int Mi = 0; Mi < 3; ++Mi)
    #pragma unroll
    for (int kk = 0; kk < 2; ++kk) wQKV[Mi][kk] = ldfrag(WF, 6 + Mi * 2 + kk, tid);
  #pragma unroll
  for (int kk = 0; kk < 2; ++kk) wOUT2[kk] = ldfrag(WF, 12 + kk, tid);

  // ---- stage constants b1..rbias (1216 floats) ----
  {
    const float2* src = reinterpret_cast<const float2*>(wsf);
    float2* dst = reinterpret_cast<float2*>(&S.b1[0]);
    for (int i = tid; i < 608; i += BLK) dst[i] = src[i];
  }
  // stage x for sub-iter 0 (16 TLs x 4 lane-rows, K padded to 32)
  {
    const int r = tid >> 2, seg = tid & 3;
    uint4 z = {0, 0, 0, 0};
    if (seg == 0) {
      const int gl = n0 * 4 + r;
      z.x = pack2(queue[gl], waiting[gl]);
      z.y = pack2(elapsed[n0 + (r >> 2)], 0.f);
    }
    *reinterpret_cast<uint4*>(&S.xbuf[r * 32 + seg * 8]) = z;
  }
  __syncthreads();

  // ================= A-part: 4 sub-iters of 16 TLs =================
  #pragma unroll 1
  for (int s = 0; s < 4; ++s) {
    const int tl0 = n0 + s * 16;

    // ---- layer1 MFMA (K=32 zero-padded): h^T = w1^T @ x, bias in acc-init ----
    {
      f32x4 acc[2][4];
      #pragma unroll
      for (int Mi = 0; Mi < 2; ++Mi) {
        const f32x4 bb = *reinterpret_cast<const f32x4*>(&S.b1[(wv * 2 + Mi) * 16 + quad * 4]);
        #pragma unroll
        for (int Nt = 0; Nt < 4; ++Nt) acc[Mi][Nt] = bb;
      }
      #pragma unroll
      for (int Nt = 0; Nt < 4; ++Nt) {
        const bfrag b = LDBACT(S.xbuf, 32, Nt, 0);
        acc[0][Nt] = mfma16(wL1[0], b, acc[0][Nt]);
        acc[1][Nt] = mfma16(wL1[1], b, acc[1][Nt]);
      }
      #pragma unroll
      for (int Mi = 0; Mi < 2; ++Mi) {
        const int oc0 = (wv * 2 + Mi) * 16 + quad * 4;
        #pragma unroll
        for (int Nt = 0; Nt < 4; ++Nt) {
          const int row = Nt * 16 + m;
          uint2 u;
          u.x = pack2(fmaxf(acc[Mi][Nt][0], 0.f), fmaxf(acc[Mi][Nt][1], 0.f));
          u.y = pack2(fmaxf(acc[Mi][Nt][2], 0.f), fmaxf(acc[Mi][Nt][3], 0.f));
          *reinterpret_cast<uint2*>(&S.h[row * 136 + oc0]) = u;
        }
      }
    }
    __syncthreads();

    // ---- layer2: emb^T = w2^T @ h, bias in acc-init ----
    {
      const int oc0 = wv * 16 + quad * 4;
      const f32x4 bb = *reinterpret_cast<const f32x4*>(&S.b2[oc0]);
      f32x4 acc[4] = {bb, bb, bb, bb};
      #pragma unroll
      for (int Nt = 0; Nt < 4; ++Nt)
        #pragma unroll
        for (int kk = 0; kk < 4; ++kk)
          acc[Nt] = mfma16(wL2[kk], LDBACT(S.h, 136, Nt, kk), acc[Nt]);
      #pragma unroll
      for (int Nt = 0; Nt < 4; ++Nt) {
        const int row = Nt * 16 + m;
        uint2 u;
        u.x = pack2(fmaxf(acc[Nt][0], 0.f), fmaxf(acc[Nt][1], 0.f));
        u.y = pack2(fmaxf(acc[Nt][2], 0.f), fmaxf(acc[Nt][3], 0.f));
        *reinterpret_cast<uint2*>(&S.emb[row * 72 + oc0]) = u;
      }
    }
    __syncthreads();

    // ---- QKV: qkv^T = Win^T @ emb (bf16 out), bias in acc-init; stage next x ----
    {
      f32x4 acc[3][4];
      #pragma unroll
      for (int Mi = 0; Mi < 3; ++Mi) {
        const f32x4 bb = *reinterpret_cast<const f32x4*>(&S.bin[(wv + Mi * 4) * 16 + quad * 4]);
        #pragma unroll
        for (int Nt = 0; Nt < 4; ++Nt) acc[Mi][Nt] = bb;
      }
      #pragma unroll
      for (int Nt = 0; Nt < 4; ++Nt) {
        const bfrag e0 = LDBACT(S.emb, 72, Nt, 0);
        const bfrag e1 = LDBACT(S.emb, 72, Nt, 1);
        #pragma unroll
        for (int Mi = 0; Mi < 3; ++Mi) {
          acc[Mi][Nt] = mfma16(wQKV[Mi][0], e0, acc[Mi][Nt]);
          acc[Mi][Nt] = mfma16(wQKV[Mi][1], e1, acc[Mi][Nt]);
        }
      }
      #pragma unroll
      for (int Mi = 0; Mi < 3; ++Mi) {
        const int oc0 = (wv + Mi * 4) * 16 + quad * 4;
        #pragma unroll
        for (int Nt = 0; Nt < 4; ++Nt) {
          const int row = Nt * 16 + m;
          uint2 u;
          u.x = pack2(acc[Mi][Nt][0], acc[Mi][Nt][1]);
          u.y = pack2(acc[Mi][Nt][2], acc[Mi][Nt][3]);
          *reinterpret_cast<uint2*>(&S.qkv[row * 200 + oc0]) = u;
        }
      }
      const int r = tid >> 2, seg = tid & 3;
      uint4 z = {0, 0, 0, 0};
      if (s < 3) {      // prefetch next sub-iter's lane inputs
        if (seg == 0) {
          const int gl = (tl0 + 16) * 4 + r;
          z.x = pack2(queue[gl], waiting[gl]);
          z.y = pack2(elapsed[tl0 + 16 + (r >> 2)], 0.f);
        }
      } else {          // stage B phase-L1 input (64 TLs, K padded to 32)
        if (seg == 0) {
          const float4 p = *reinterpret_cast<const float4*>(&phase_onehot[(n0 + r) * 4]);
          z.x = pack2(p.x, p.y);
          z.y = pack2(p.z, p.w);
          z.z = pack2(elapsed[n0 + r], 0.f);
        }
      }
      *reinterpret_cast<uint4*>(&S.xbuf[r * 32 + seg * 8]) = z;
    }
    __syncthreads();

    // ---- attention: 16 threads/TL = 4 heads x 4 queries; b128 LDS reads ----
    {
      const int tl = tid >> 4, l16 = tid & 15;
      const int hh = l16 >> 2, lq = l16 & 3;
      const uint4* qp = reinterpret_cast<const uint4*>(
          &S.qkv[(tl * 4 + lq) * 200 + hh * 16]);
      const uint4 qA = qp[0], qB = qp[1];
      const unsigned int qu[8] = {qA.x, qA.y, qA.z, qA.w, qB.x, qB.y, qB.z, qB.w};
      float qlo[8], qhi[8];
      #pragma unroll
      for (int j = 0; j < 8; ++j) { qlo[j] = lo16(qu[j]); qhi[j] = hi16(qu[j]); }
      float sc[4];
      #pragma unroll
      for (int lk = 0; lk < 4; ++lk) {
        const uint4* kp = reinterpret_cast<const uint4*>(
            &S.qkv[(tl * 4 + lk) * 200 + 64 + hh * 16]);
        const uint4 kA = kp[0], kB = kp[1];
        const unsigned int ku[8] = {kA.x, kA.y, kA.z, kA.w, kB.x, kB.y, kB.z, kB.w};
        float tx = 0.f, ty = 0.f;
        #pragma unroll
        for (int j = 0; j < 8; ++j) {
          tx += qlo[j] * lo16(ku[j]);
          ty += qhi[j] * hi16(ku[j]);
        }
        sc[lk] = tx + ty;   // 1/sqrt(HD) folded into Q weights/bias
      }
      const float mx = fmaxf(fmaxf(sc[0], sc[1]), fmaxf(sc[2], sc[3]));
      const float e0 = __expf(sc[0] - mx), e1 = __expf(sc[1] - mx);
      const float e2 = __expf(sc[2] - mx), e3 = __expf(sc[3] - mx);
      const float inv = 1.f / (e0 + e1 + e2 + e3);
      const float pr[4] = {e0 * inv, e1 * inv, e2 * inv, e3 * inv};
      float olo[8], ohi[8];
      #pragma unroll
      for (int j = 0; j < 8; ++j) { olo[j] = 0.f; ohi[j] = 0.f; }
      #pragma unroll
      for (int lk = 0; lk < 4; ++lk) {
        const uint4* vp = reinterpret_cast<const uint4*>(
            &S.qkv[(tl * 4 + lk) * 200 + 128 + hh * 16]);
        const uint4 vA = vp[0], vB = vp[1];
        const unsigned int vu[8] = {vA.x, vA.y, vA.z, vA.w, vB.x, vB.y, vB.z, vB.w};
        const float p = pr[lk];
        #pragma unroll
        for (int j = 0; j < 8; ++j) {
          olo[j] += p * lo16(vu[j]);
          ohi[j] += p * hi16(vu[j]);
        }
      }
      // mean over queries folded into wOUT; raw o -> om[tl][lq*64 + hh*16 + d]
      unsigned short* om = S.emb;
      const int base = tl * 264 + lq * 64 + hh * 16;
      *reinterpret_cast<uint4*>(&om[base]) =
          make_uint4(pack2(olo[0], ohi[0]), pack2(olo[1], ohi[1]),
                     pack2(olo[2], ohi[2]), pack2(olo[3], ohi[3]));
      *reinterpret_cast<uint4*>(&om[base + 8]) =
          make_uint4(pack2(olo[4], ohi[4]), pack2(olo[5], ohi[5]),
                     pack2(olo[6], ohi[6]), pack2(olo[7], ohi[7]));
    }
    __syncthreads();

    // ---- out-proj (K=256, mean folded), bias in acc-init -> ctx rows s*16.. ----
    {
      const int oc0 = wv * 16 + quad * 4;
      f32x4 acc = *reinterpret_cast<const f32x4*>(&S.bout[oc0]);
      #pragma unroll
      for (int kk = 0; kk < 8; ++kk)
        acc = mfma16(wOUT2[kk & 1], LDBACT(S.emb, 264, 0, kk), acc);
      uint2 u;
      u.x = pack2(acc[0], acc[1]);
      u.y = pack2(acc[2], acc[3]);
      *reinterpret_cast<uint2*>(&S.ctx[(s * 16 + m) * 72 + oc0]) = u;
    }
    // no barrier: next layer1 writes S.h (attn readers of qkv passed barrier);
    // ctx readers are behind the post-loop barrier.
  }
  __syncthreads();

  // ================= B-part: 64 TLs =================
  // B-part weight fragments loaded HERE so their live range does not overlap
  // the A-part fragments (earlier up-front load -> scratch spill).
  __builtin_amdgcn_sched_barrier(0);
  bfrag wP1[2], wP2[2][4], wH1[2][6];
  #pragma unroll
  for (int Mi = 0; Mi < 2; ++Mi) {
    wP1[Mi] = ldfrag(WF, 14 + Mi, tid);
    #pragma unroll
    for (int kk = 0; kk < 4; ++kk) wP2[Mi][kk] = ldfrag(WF, 16 + Mi * 4 + kk, tid);
    #pragma unroll
    for (int kk = 0; kk < 6; ++kk) wH1[Mi][kk] = ldfrag(WF, 24 + Mi * 6 + kk, tid);
  }

  // ---- phase L1 MFMA (K=32 zero-padded), bias in acc-init -> ph ----
  {
    f32x4 acc[2][4];
    #pragma unroll
    for (int Mi = 0; Mi < 2; ++Mi) {
      const f32x4 bb = *reinterpret_cast<const f32x4*>(&S.pb1[(wv * 2 + Mi) * 16 + quad * 4]);
      #pragma unroll
      for (int Nt = 0; Nt < 4; ++Nt) acc[Mi][Nt] = bb;
    }
    #pragma unroll
    for (int Nt = 0; Nt < 4; ++Nt) {
      const bfrag b = LDBACT(S.xbuf, 32, Nt, 0);
      acc[0][Nt] = mfma16(wP1[0], b, acc[0][Nt]);
      acc[1][Nt] = mfma16(wP1[1], b, acc[1][Nt]);
    }
    #pragma unroll
    for (int Mi = 0; Mi < 2; ++Mi) {
      const int oc0 = (wv * 2 + Mi) * 16 + quad * 4;
      #pragma unroll
      for (int Nt = 0; Nt < 4; ++Nt) {
        const int row = Nt * 16 + m;
        uint2 u;
        u.x = pack2(fmaxf(acc[Mi][Nt][0], 0.f), fmaxf(acc[Mi][Nt][1], 0.f));
        u.y = pack2(fmaxf(acc[Mi][Nt][2], 0.f), fmaxf(acc[Mi][Nt][3], 0.f));
        *reinterpret_cast<uint2*>(&S.ph[row * 136 + oc0]) = u;
      }
    }
  }
  __syncthreads();

  // ---- phase L2 (K=128), bias in acc-init -> pl2out (overlay, stride 136) ----
  {
    f32x4 acc[2][4];
    #pragma unroll
    for (int Mi = 0; Mi < 2; ++Mi) {
      const f32x4 bb = *reinterpret_cast<const f32x4*>(&S.pb2[(wv * 2 + Mi) * 16 + quad * 4]);
      #pragma unroll
      for (int Nt = 0; Nt < 4; ++Nt) acc[Mi][Nt] = bb;
    }
    #pragma unroll
    for (int kk = 0; kk < 4; ++kk)
      #pragma unroll
      for (int Nt = 0; Nt < 4; ++Nt) {
        const bfrag b = LDBACT(S.ph, 136, Nt, kk);
        acc[0][Nt] = mfma16(wP2[0][kk], b, acc[0][Nt]);
        acc[1][Nt] = mfma16(wP2[1][kk], b, acc[1][Nt]);
      }
    #pragma unroll
    for (int Mi = 0; Mi < 2; ++Mi) {
      const int oc0 = (wv * 2 + Mi) * 16 + quad * 4;
      #pragma unroll
      for (int Nt = 0; Nt < 4; ++Nt) {
        const int row = Nt * 16 + m;
        uint2 u;
        u.x = pack2(fmaxf(acc[Mi][Nt][0], 0.f), fmaxf(acc[Mi][Nt][1], 0.f));
        u.y = pack2(fmaxf(acc[Mi][Nt][2], 0.f), fmaxf(acc[Mi][Nt][3], 0.f));
        *reinterpret_cast<uint2*>(&pl2out[row * 136 + oc0]) = u;
      }
    }
  }
  __syncthreads();

  // ---- head L1 (K=192): kk 0-1 from ctx, kk 2-5 from pl2out; rbias acc-init ----
  {
    int rg[4];
    #pragma unroll
    for (int Nt = 0; Nt < 4; ++Nt) {
      int g = region_ids[n0 + Nt * 16 + m];
      rg[Nt] = g < 0 ? 0 : (g > 3 ? 3 : g);
    }
    f32x4 acc[2][4];
    #pragma unroll
    for (int Mi = 0; Mi < 2; ++Mi) {
      const int oc0 = (wv * 2 + Mi) * 16 + quad * 4;
      #pragma unroll
      for (int Nt = 0; Nt < 4; ++Nt)
        acc[Mi][Nt] = *reinterpret_cast<const f32x4*>(&S.rbias[rg[Nt]][oc0]);
    }
    #pragma unroll
    for (int kk = 0; kk < 2; ++kk)
      #pragma unroll
      for (int Nt = 0; Nt < 4; ++Nt) {
        const bfrag b = LDBACT(S.ctx, 72, Nt, kk);
        acc[0][Nt] = mfma16(wH1[0][kk], b, acc[0][Nt]);
        acc[1][Nt] = mfma16(wH1[1][kk], b, acc[1][Nt]);
      }
    #pragma unroll
    for (int kk = 2; kk < 6; ++kk)
      #pragma unroll
      for (int Nt = 0; Nt < 4; ++Nt) {
        const bfrag b = LDBACT(pl2out, 136, Nt, kk - 2);
        acc[0][Nt] = mfma16(wH1[0][kk], b, acc[0][Nt]);
        acc[1][Nt] = mfma16(wH1[1][kk], b, acc[1][Nt]);
      }
    #pragma unroll
    for (int Mi = 0; Mi < 2; ++Mi) {
      const int oc0 = (wv * 2 + Mi) * 16 + quad * 4;
      #pragma unroll
      for (int Nt = 0; Nt < 4; ++Nt) {
        const int row = Nt * 16 + m;
        uint2 u;
        u.x = pack2(fmaxf(acc[Mi][Nt][0], 0.f), fmaxf(acc[Mi][Nt][1], 0.f));
        u.y = pack2(fmaxf(acc[Mi][Nt][2], 0.f), fmaxf(acc[Mi][Nt][3], 0.f));
        *reinterpret_cast<uint2*>(&S.ph[row * 136 + oc0]) = u;
      }
    }
  }
  __syncthreads();

  // ---- head L2 (128->1) + gaussian: 4 threads/TL; hw2/consts from L2 consts ----
  {
    const int tl = tid >> 2, s4 = tid & 3;   // 64 TLs x 4 threads
    const float* hw2g = wsf + 1216;
    const uint4* hp = reinterpret_cast<const uint4*>(&S.ph[tl * 136 + s4 * 32]);
    const uint4 h0 = hp[0], h1 = hp[1], h2 = hp[2], h3 = hp[3];
    const unsigned int hu[16] = {h0.x, h0.y, h0.z, h0.w, h1.x, h1.y, h1.z, h1.w,
                                 h2.x, h2.y, h2.z, h2.w, h3.x, h3.y, h3.z, h3.w};
    float t = 0.f;
    #pragma unroll
    for (int j = 0; j < 16; ++j) {
      t += lo16(hu[j]) * hw2g[s4 * 32 + 2 * j];
      t += hi16(hu[j]) * hw2g[s4 * 32 + 2 * j + 1];
    }
    t += __shfl_xor(t, 1);
    t += __shfl_xor(t, 2);
    if (s4 == 0) {
      const int n = n0 + tl;
      const float means = t + wsf[1344];
      const float ls = wsf[1345];
      const float nz = noise[n];
      const float a = means + __expf(ls) * nz;
      out[n] = fminf(fmaxf(a, -1.f), 1.f);
      // (actions - means) == std*noise exactly -> log_prob independent of means
      out[N_TL + n] = -0.5f * (nz * nz + 2.f * ls + 1.8378770664093453f);
    }
  }
}

extern "C" void kernel_launch(void* const* d_in, const int* in_sizes, int n_in,
                              void* d_out, int out_size, void* d_ws, size_t ws_size,
                              hipStream_t stream) {
  const float* queue        = (const float*)d_in[0];
  const float* waiting      = (const float*)d_in[1];
  const float* phase_onehot = (const float*)d_in[2];
  const float* elapsed      = (const float*)d_in[3];
  const int*   region_ids   = (const int*)d_in[4];
  const float* noise        = (const float*)d_in[5];
  const float* lane_w1      = (const float*)d_in[6];
  const float* lane_b1      = (const float*)d_in[7];
  const float* lane_w2      = (const float*)d_in[8];
  const float* lane_b2      = (const float*)d_in[9];
  const float* attn_in_w    = (const float*)d_in[10];
  const float* attn_in_b    = (const float*)d_in[11];
  const float* attn_out_w   = (const float*)d_in[12];
  const float* attn_out_b   = (const float*)d_in[13];
  const float* phase_w1     = (const float*)d_in[14];
  const float* phase_b1     = (const float*)d_in[15];
  const float* phase_w2     = (const float*)d_in[16];
  const float* phase_b2     = (const float*)d_in[17];
  const float* region_table = (const float*)d_in[18];
  const float* head_w1      = (const float*)d_in[19];
  const float* head_b1      = (const float*)d_in[20];
  const float* head_w2      = (const float*)d_in[21];
  const float* head_b2      = (const float*)d_in[22];
  const float* log_std      = (const float*)d_in[23];

  float* out = (float*)d_out;
  uint4* ws  = (uint4*)d_ws;       // 36*256*16B frag table + 1346 f32 consts (~153 KB)
  (void)ws_size;

  hipLaunchKernelGGL(prep_weights, dim3(NFRAG), dim3(BLK), 0, stream,
                     lane_w1, lane_b1, lane_w2, lane_b2,
                     attn_in_w, attn_in_b, attn_out_w, attn_out_b,
                     phase_w1, phase_b1, phase_w2, phase_b2, region_table,
                     head_w1, head_b1, head_w2, head_b2, log_std, ws);

  hipLaunchKernelGGL(fused_policy, dim3(GRID), dim3(BLK), 0, stream,
                     queue, waiting, phase_onehot, elapsed, region_ids, noise,
                     (const uint4*)ws, out);
}